// Round 8
// baseline (213.088 us; speedup 1.0000x reference)
//
#include <hip/hip_runtime.h>

// MultiHeadGraphAttention: B=8, N=1024, IN=OUT=256, H=8, d_k=32
// prep(cvt + fused mask/dist bias fp16) -> QKV gemm (bf16 MFMA, Q pre-scaled)
// -> fused masked attention (S^T/O^T, fixed-max exp2 softmax, FULLY-UNROLLED
//    16x64-key loop with immediate-offset loads, lag-one P LDS double buffer,
//    XCD-affine blocks) -> out proj.

typedef __bf16 bf16x8 __attribute__((ext_vector_type(8)));
typedef __bf16 bf16x4 __attribute__((ext_vector_type(4)));
typedef float f32x4 __attribute__((ext_vector_type(4)));
typedef int i32x4 __attribute__((ext_vector_type(4)));

#define DEV static __device__ __forceinline__

#define LOG2E 1.4426950408889634f
#define QSCALE 0.2550351062f   // (1/sqrt(32)) * log2(e)

DEV unsigned short f2bf(float f) {   // RNE f32 -> bf16 bits
  union { float f; unsigned u; } x; x.f = f;
  unsigned r = x.u + 0x7fffu + ((x.u >> 16) & 1u);
  return (unsigned short)(r >> 16);
}

DEV unsigned short f2h(float f) {    // f32 -> fp16 bits (RNE)
  _Float16 h = (_Float16)f;
  unsigned short u;
  __builtin_memcpy(&u, &h, 2);
  return u;
}

DEV float h2f(unsigned short u) {    // fp16 bits -> f32
  _Float16 h;
  __builtin_memcpy(&h, &u, 2);
  return (float)h;
}

DEV f32x4 mfma16(bf16x8 a, bf16x8 b, f32x4 c) {
  return __builtin_amdgcn_mfma_f32_16x16x32_bf16(a, b, c, 0, 0, 0);
}

DEV bf16x8 ldfrag(const unsigned short* p) {
  return *reinterpret_cast<const bf16x8*>(p);
}

// ---------------- prep ---------------------------------------------------------
// range 0: Bias[b][q][k] fp16 = A<=0 ? -60000 : -ds*log2e*D   (4 elems/thread)
// range 1: X f32 -> bf16 ; range 2: W -> bf16 transposed [n][k]
__global__ __launch_bounds__(256) void k_prep(
    const float* __restrict__ X, const int* __restrict__ A,
    const float* __restrict__ D, const float* __restrict__ dscale,
    const float* __restrict__ Wq, const float* __restrict__ Wk,
    const float* __restrict__ Wv, const float* __restrict__ Wo,
    unsigned short* __restrict__ Xbf, unsigned short* __restrict__ Wt,
    unsigned short* __restrict__ Bias) {
  const int tid = blockIdx.x * 256 + threadIdx.x;
  const int NB4 = (8 * 1024 * 1024) / 4;      // 2,097,152 bias quads
  const int NX4 = (8192 * 256) / 4;           //   524,288 X quads
  if (tid < NB4) {
    const i32x4 a4 = reinterpret_cast<const i32x4*>(A)[tid];
    const f32x4 d4 = reinterpret_cast<const f32x4*>(D)[tid];
    const float c = -dscale[0] * LOG2E;
    ushort4 o;
    unsigned short* op = (unsigned short*)&o;
    #pragma unroll
    for (int i = 0; i < 4; ++i)
      op[i] = f2h(a4[i] <= 0 ? -60000.0f : c * d4[i]);
    reinterpret_cast<ushort4*>(Bias)[tid] = o;
  } else if (tid < NB4 + NX4) {
    const int t = tid - NB4;
    float4 v = reinterpret_cast<const float4*>(X)[t];
    ushort4 o;
    o.x = f2bf(v.x); o.y = f2bf(v.y); o.z = f2bf(v.z); o.w = f2bf(v.w);
    reinterpret_cast<ushort4*>(Xbf)[t] = o;
  } else {
    int t = tid - NB4 - NX4;                  // 0 .. 262143
    int mat = t >> 16;
    int e = t & 65535;
    int n = e >> 8, k = e & 255;              // output Wt[mat][n][k]
    const float* W = (mat == 0) ? Wq : (mat == 1) ? Wk : (mat == 2) ? Wv : Wo;
    Wt[t] = f2bf(W[k * 256 + n]);
  }
}

// ---------------- QKV projection GEMM -----------------------------------------
// grid (512, 3): x = m-tile of 16, y = matrix (0=Q 1=K 2=V). block 256 (4 waves).
__global__ __launch_bounds__(256, 2) void k_qkv(
    const unsigned short* __restrict__ Xbf, const unsigned short* __restrict__ Wt,
    const float* __restrict__ bq, const float* __restrict__ bk,
    const float* __restrict__ bv,
    unsigned short* __restrict__ Qb, unsigned short* __restrict__ Kb,
    unsigned short* __restrict__ Vt) {
  const int lane = threadIdx.x & 63;
  const int w = threadIdx.x >> 6;
  const int lr = lane & 15, lg = lane >> 4;
  const int m0 = blockIdx.x << 4;
  const int mat = blockIdx.y;

  bf16x8 a[8];
  #pragma unroll
  for (int ks = 0; ks < 8; ++ks)
    a[ks] = ldfrag(Xbf + (m0 + lr) * 256 + ks * 32 + lg * 8);

  const unsigned short* Wm = Wt + mat * 65536;
  const float* bias = (mat == 0) ? bq : (mat == 1) ? bk : bv;

  #pragma unroll
  for (int nb = 0; nb < 4; ++nb) {
    const int nloc = nb * 64 + w * 16;
    bf16x8 bfr[8];
    #pragma unroll
    for (int ks = 0; ks < 8; ++ks)
      bfr[ks] = ldfrag(Wm + (nloc + lr) * 256 + ks * 32 + lg * 8);
    f32x4 acc = {0.f, 0.f, 0.f, 0.f};
    #pragma unroll
    for (int ks = 0; ks < 8; ++ks)
      acc = mfma16(a[ks], bfr[ks], acc);
    const float bb = bias[nloc + lr];
    const int cm = nloc + lr;
    const int hh = cm >> 5, d = cm & 31;
    if (mat == 2) {                           // V transposed: 4 consecutive halfs
      ushort4 vv;
      unsigned short* vp = (unsigned short*)&vv;
      #pragma unroll
      for (int i = 0; i < 4; ++i) vp[i] = f2bf(acc[i] + bb);
      const int row = m0 + lg * 4;
      const int bidx = row >> 10, nn = row & 1023;
      *reinterpret_cast<ushort4*>(&Vt[(((bidx * 8 + hh) * 32) + d) * 1024 + nn]) = vv;
    } else if (mat == 0) {
      #pragma unroll
      for (int i = 0; i < 4; ++i) {
        const int row = m0 + lg * 4 + i;
        const int bidx = row >> 10, nn = row & 1023;
        Qb[(((bidx * 8 + hh) * 1024) + nn) * 32 + d] = f2bf((acc[i] + bb) * QSCALE);
      }
    } else {
      #pragma unroll
      for (int i = 0; i < 4; ++i) {
        const int row = m0 + lg * 4 + i;
        const int bidx = row >> 10, nn = row & 1023;
        Kb[(((bidx * 8 + hh) * 1024) + nn) * 32 + d] = f2bf(acc[i] + bb);
      }
    }
  }
}

// ---------------- fused masked attention --------------------------------------
// grid 512: b = bi&7 (XCD-affine), q0 = (bi>>3)*16. block 512 = 8 waves = heads.
// FULLY UNROLLED 16 iterations of 64 keys: all load addresses become
// base + immediate offset; no barriers anywhere (P buffer is wave-private), so
// the scheduler can hoist loads across iterations up to the VGPR cap.
// Fixed-max softmax: p = exp2(s + bias), masked -> exact 0; 4 parallel psum
// accumulators, reduced once at the end. P lag-one LDS double buffer.
__global__ __launch_bounds__(512, 4) void k_attn(
    const unsigned short* __restrict__ Qb, const unsigned short* __restrict__ Kb,
    const unsigned short* __restrict__ Vt, const unsigned short* __restrict__ Bias,
    unsigned short* __restrict__ AO) {
  __shared__ unsigned short P[8][2][16][72];  // [head][buf][q][64 keys + pad]
  const int lane = threadIdx.x & 63;
  const int h = threadIdx.x >> 6;
  const int lr = lane & 15, lg = lane >> 4;
  const int b = blockIdx.x & 7;               // XCD affinity: batch b -> XCD b
  const int q0 = (blockIdx.x >> 3) << 4;

  const unsigned short* Qh = Qb + (size_t)((b * 8 + h) * 1024) * 32;
  const unsigned short* Kh = Kb + (size_t)((b * 8 + h) * 1024) * 32 + lr * 32 + lg * 8;
  const unsigned short* Vh = Vt + (size_t)((b * 8 + h) * 32) * 1024 + lr * 1024 + lg * 8;
  const unsigned short* Brow = Bias + ((size_t)b << 20) + (size_t)(q0 + lr) * 1024 + lg * 4;

  const bf16x8 qf = ldfrag(Qh + (q0 + lr) * 32 + lg * 8);

  f32x4 o0 = {0.f, 0.f, 0.f, 0.f}, o1 = {0.f, 0.f, 0.f, 0.f};
  f32x4 ps = {0.f, 0.f, 0.f, 0.f};            // 4 parallel psum accumulators

  bf16x8 vprev0[2], vprev1[2];                // V(t-1) fragments for lagged PV

  #pragma unroll
  for (int t = 0; t < 16; ++t) {
    const int k0 = t << 6;                    // compile-time constant

    // ---- loads for tile t (immediate offsets off fixed base pointers) ----
    bf16x8 kf[4];
    #pragma unroll
    for (int st = 0; st < 4; ++st)
      kf[st] = ldfrag(Kh + (k0 + st * 16) * 32);
    bf16x8 vf00 = ldfrag(Vh + k0);
    bf16x8 vf01 = ldfrag(Vh + k0 + 32);
    bf16x8 vf10 = ldfrag(Vh + 16 * 1024 + k0);
    bf16x8 vf11 = ldfrag(Vh + 16 * 1024 + k0 + 32);
    ushort4 bb[4];
    #pragma unroll
    for (int st = 0; st < 4; ++st)
      bb[st] = *reinterpret_cast<const ushort4*>(Brow + k0 + st * 16);

    // ---- QK^T: s[st] rows = keys k0+st*16+lg*4+i, cols = q (lane lr) ----
    const f32x4 zz = {0.f, 0.f, 0.f, 0.f};
    f32x4 s[4];
    #pragma unroll
    for (int st = 0; st < 4; ++st)
      s[st] = mfma16(kf[st], qf, zz);

    // ---- read P(t-1) (issued early; completes under exp/pack below) ----
    bf16x8 pf0, pf1;
    if (t > 0) {
      const unsigned short* pb = &P[h][(t - 1) & 1][lr][0];
      pf0 = *reinterpret_cast<const bf16x8*>(pb + lg * 8);
      pf1 = *reinterpret_cast<const bf16x8*>(pb + 32 + lg * 8);
    }

    // ---- p = exp2(s + bias); masked bias = -60000 -> exp2 underflows to 0 ----
    float p[4][4];
    #pragma unroll
    for (int st = 0; st < 4; ++st) {
      const unsigned short* bp = (const unsigned short*)&bb[st];
      #pragma unroll
      for (int i = 0; i < 4; ++i) {
        p[st][i] = exp2f(s[st][i] + h2f(bp[i]));
        ps[st] += p[st][i];
      }
    }

    // ---- pack P(t) -> LDS buf[t&1] ----
    #pragma unroll
    for (int st = 0; st < 4; ++st) {
      bf16x4 pw;
      #pragma unroll
      for (int i = 0; i < 4; ++i) pw[i] = (__bf16)p[st][i];
      *reinterpret_cast<bf16x4*>(&P[h][t & 1][lr][st * 16 + lg * 4]) = pw;
    }

    // ---- PV(t-1) with V(t-1) ----
    if (t > 0) {
      o0 = mfma16(vprev0[0], pf0, o0);
      o0 = mfma16(vprev0[1], pf1, o0);
      o1 = mfma16(vprev1[0], pf0, o1);
      o1 = mfma16(vprev1[1], pf1, o1);
    }
    vprev0[0] = vf00; vprev0[1] = vf01;
    vprev1[0] = vf10; vprev1[1] = vf11;
  }

  // epilogue: PV(15)
  {
    const unsigned short* pb = &P[h][1][lr][0];
    const bf16x8 pf0 = *reinterpret_cast<const bf16x8*>(pb + lg * 8);
    const bf16x8 pf1 = *reinterpret_cast<const bf16x8*>(pb + 32 + lg * 8);
    o0 = mfma16(vprev0[0], pf0, o0);
    o0 = mfma16(vprev0[1], pf1, o0);
    o1 = mfma16(vprev1[0], pf0, o1);
    o1 = mfma16(vprev1[1], pf1, o1);
  }

  float psum = ps[0] + ps[1] + ps[2] + ps[3];
  psum += __shfl_xor(psum, 16);
  psum += __shfl_xor(psum, 32);
  const float linv = 1.0f / psum;             // per-lane (q = lr)

  ushort4 r0, r1;
  unsigned short* r0p = (unsigned short*)&r0;
  unsigned short* r1p = (unsigned short*)&r1;
  #pragma unroll
  for (int i = 0; i < 4; ++i) {
    r0p[i] = f2bf(o0[i] * linv);
    r1p[i] = f2bf(o1[i] * linv);
  }
  const int row = (b << 10) + q0 + lr;
  *reinterpret_cast<ushort4*>(&AO[row * 256 + h * 32 + lg * 4]) = r0;
  *reinterpret_cast<ushort4*>(&AO[row * 256 + h * 32 + 16 + lg * 4]) = r1;
}

// ---------------- output projection -------------------------------------------
// grid (512, 2): x = m-tile of 16, y = 128-col half.
__global__ __launch_bounds__(256, 2) void k_oproj(
    const unsigned short* __restrict__ AO, const unsigned short* __restrict__ Wto,
    const float* __restrict__ bo, float* __restrict__ out) {
  const int lane = threadIdx.x & 63;
  const int w = threadIdx.x >> 6;
  const int lr = lane & 15, lg = lane >> 4;
  const int m0 = blockIdx.x << 4;

  bf16x8 a[8];
  #pragma unroll
  for (int ks = 0; ks < 8; ++ks)
    a[ks] = ldfrag(AO + (m0 + lr) * 256 + ks * 32 + lg * 8);

  #pragma unroll
  for (int j = 0; j < 2; ++j) {
    const int c0 = (blockIdx.y * 2 + j) * 64 + w * 16;
    bf16x8 bfr[8];
    #pragma unroll
    for (int ks = 0; ks < 8; ++ks)
      bfr[ks] = ldfrag(Wto + (c0 + lr) * 256 + ks * 32 + lg * 8);
    f32x4 acc = {0.f, 0.f, 0.f, 0.f};
    #pragma unroll
    for (int ks = 0; ks < 8; ++ks)
      acc = mfma16(a[ks], bfr[ks], acc);
    const float bb = bo[c0 + lr];
    #pragma unroll
    for (int i = 0; i < 4; ++i) {
      const int row = m0 + lg * 4 + i;
      out[row * 256 + c0 + lr] = acc[i] + bb;
    }
  }
}

extern "C" void kernel_launch(void* const* d_in, const int* in_sizes, int n_in,
                              void* d_out, int out_size, void* d_ws, size_t ws_size,
                              hipStream_t stream) {
  const float* X   = (const float*)d_in[0];
  const int*   A   = (const int*)d_in[1];
  const float* D   = (const float*)d_in[2];
  const float* Wq  = (const float*)d_in[3];
  const float* bq  = (const float*)d_in[4];
  const float* Wk  = (const float*)d_in[5];
  const float* bk  = (const float*)d_in[6];
  const float* Wv  = (const float*)d_in[7];
  const float* bv  = (const float*)d_in[8];
  const float* Wo  = (const float*)d_in[9];
  const float* bo  = (const float*)d_in[10];
  const float* dsc = (const float*)d_in[11];
  float* out = (float*)d_out;

  unsigned short* ws = (unsigned short*)d_ws;
  unsigned short* Xbf  = ws;                   // 2,097,152  (reused as AO later)
  unsigned short* Wt   = ws + 2097152;         //   262,144
  unsigned short* Qb   = ws + 2359296;         // 2,097,152
  unsigned short* Kb   = ws + 4456448;         // 2,097,152
  unsigned short* Vt   = ws + 6553600;         // 2,097,152
  unsigned short* Bias = ws + 8650752;         // 8,388,608  (total ~34.1 MB)
  unsigned short* AO   = Xbf;                  // alias: Xbf dead after k_qkv

  hipLaunchKernelGGL(k_prep, dim3(11264), dim3(256), 0, stream,
                     X, A, D, dsc, Wq, Wk, Wv, Wo, Xbf, Wt, Bias);
  hipLaunchKernelGGL(k_qkv, dim3(512, 3), dim3(256), 0, stream,
                     Xbf, Wt, bq, bk, bv, Qb, Kb, Vt);
  hipLaunchKernelGGL(k_attn, dim3(512), dim3(512), 0, stream,
                     Qb, Kb, Vt, Bias, AO);
  hipLaunchKernelGGL(k_oproj, dim3(512, 2), dim3(256), 0, stream,
                     AO, Wt + 196608, bo, out);
}

// Round 9
// 137.735 us; speedup vs baseline: 1.5471x; 1.5471x over previous
//
#include <hip/hip_runtime.h>

// MultiHeadGraphAttention: B=8, N=1024, IN=OUT=256, H=8, d_k=32
// prep(cvt + fused mask/dist bias fp16) -> QKV gemm (bf16 MFMA, Q pre-scaled)
// -> fused masked attention (S^T/O^T, fixed-max exp2 softmax, 2-way key-split
//    across wave pairs + LDS combine, XCD-affine blocks) -> out proj.

typedef __bf16 bf16x8 __attribute__((ext_vector_type(8)));
typedef __bf16 bf16x4 __attribute__((ext_vector_type(4)));
typedef float f32x4 __attribute__((ext_vector_type(4)));
typedef int i32x4 __attribute__((ext_vector_type(4)));

#define DEV static __device__ __forceinline__

#define LOG2E 1.4426950408889634f
#define QSCALE 0.2550351062f   // (1/sqrt(32)) * log2(e)

DEV unsigned short f2bf(float f) {   // RNE f32 -> bf16 bits
  union { float f; unsigned u; } x; x.f = f;
  unsigned r = x.u + 0x7fffu + ((x.u >> 16) & 1u);
  return (unsigned short)(r >> 16);
}

DEV unsigned short f2h(float f) {    // f32 -> fp16 bits (RNE)
  _Float16 h = (_Float16)f;
  unsigned short u;
  __builtin_memcpy(&u, &h, 2);
  return u;
}

DEV float h2f(unsigned short u) {    // fp16 bits -> f32
  _Float16 h;
  __builtin_memcpy(&h, &u, 2);
  return (float)h;
}

DEV f32x4 mfma16(bf16x8 a, bf16x8 b, f32x4 c) {
  return __builtin_amdgcn_mfma_f32_16x16x32_bf16(a, b, c, 0, 0, 0);
}

DEV bf16x8 ldfrag(const unsigned short* p) {
  return *reinterpret_cast<const bf16x8*>(p);
}

// ---------------- prep ---------------------------------------------------------
// range 0: Bias[b][q][k] fp16 = A<=0 ? -60000 : -ds*log2e*D   (4 elems/thread)
// range 1: X f32 -> bf16 ; range 2: W -> bf16 transposed [n][k]
__global__ __launch_bounds__(256) void k_prep(
    const float* __restrict__ X, const int* __restrict__ A,
    const float* __restrict__ D, const float* __restrict__ dscale,
    const float* __restrict__ Wq, const float* __restrict__ Wk,
    const float* __restrict__ Wv, const float* __restrict__ Wo,
    unsigned short* __restrict__ Xbf, unsigned short* __restrict__ Wt,
    unsigned short* __restrict__ Bias) {
  const int tid = blockIdx.x * 256 + threadIdx.x;
  const int NB4 = (8 * 1024 * 1024) / 4;      // 2,097,152 bias quads
  const int NX4 = (8192 * 256) / 4;           //   524,288 X quads
  if (tid < NB4) {
    const i32x4 a4 = reinterpret_cast<const i32x4*>(A)[tid];
    const f32x4 d4 = reinterpret_cast<const f32x4*>(D)[tid];
    const float c = -dscale[0] * LOG2E;
    ushort4 o;
    unsigned short* op = (unsigned short*)&o;
    #pragma unroll
    for (int i = 0; i < 4; ++i)
      op[i] = f2h(a4[i] <= 0 ? -60000.0f : c * d4[i]);
    reinterpret_cast<ushort4*>(Bias)[tid] = o;
  } else if (tid < NB4 + NX4) {
    const int t = tid - NB4;
    float4 v = reinterpret_cast<const float4*>(X)[t];
    ushort4 o;
    o.x = f2bf(v.x); o.y = f2bf(v.y); o.z = f2bf(v.z); o.w = f2bf(v.w);
    reinterpret_cast<ushort4*>(Xbf)[t] = o;
  } else {
    int t = tid - NB4 - NX4;                  // 0 .. 262143
    int mat = t >> 16;
    int e = t & 65535;
    int n = e >> 8, k = e & 255;              // output Wt[mat][n][k]
    const float* W = (mat == 0) ? Wq : (mat == 1) ? Wk : (mat == 2) ? Wv : Wo;
    Wt[t] = f2bf(W[k * 256 + n]);
  }
}

// ---------------- QKV projection GEMM -----------------------------------------
// grid (512, 3): x = m-tile of 16, y = matrix (0=Q 1=K 2=V). block 256 (4 waves).
__global__ __launch_bounds__(256, 2) void k_qkv(
    const unsigned short* __restrict__ Xbf, const unsigned short* __restrict__ Wt,
    const float* __restrict__ bq, const float* __restrict__ bk,
    const float* __restrict__ bv,
    unsigned short* __restrict__ Qb, unsigned short* __restrict__ Kb,
    unsigned short* __restrict__ Vt) {
  const int lane = threadIdx.x & 63;
  const int w = threadIdx.x >> 6;
  const int lr = lane & 15, lg = lane >> 4;
  const int m0 = blockIdx.x << 4;
  const int mat = blockIdx.y;

  bf16x8 a[8];
  #pragma unroll
  for (int ks = 0; ks < 8; ++ks)
    a[ks] = ldfrag(Xbf + (m0 + lr) * 256 + ks * 32 + lg * 8);

  const unsigned short* Wm = Wt + mat * 65536;
  const float* bias = (mat == 0) ? bq : (mat == 1) ? bk : bv;

  #pragma unroll
  for (int nb = 0; nb < 4; ++nb) {
    const int nloc = nb * 64 + w * 16;
    bf16x8 bfr[8];
    #pragma unroll
    for (int ks = 0; ks < 8; ++ks)
      bfr[ks] = ldfrag(Wm + (nloc + lr) * 256 + ks * 32 + lg * 8);
    f32x4 acc = {0.f, 0.f, 0.f, 0.f};
    #pragma unroll
    for (int ks = 0; ks < 8; ++ks)
      acc = mfma16(a[ks], bfr[ks], acc);
    const float bb = bias[nloc + lr];
    const int cm = nloc + lr;
    const int hh = cm >> 5, d = cm & 31;
    if (mat == 2) {                           // V transposed: 4 consecutive halfs
      ushort4 vv;
      unsigned short* vp = (unsigned short*)&vv;
      #pragma unroll
      for (int i = 0; i < 4; ++i) vp[i] = f2bf(acc[i] + bb);
      const int row = m0 + lg * 4;
      const int bidx = row >> 10, nn = row & 1023;
      *reinterpret_cast<ushort4*>(&Vt[(((bidx * 8 + hh) * 32) + d) * 1024 + nn]) = vv;
    } else if (mat == 0) {
      #pragma unroll
      for (int i = 0; i < 4; ++i) {
        const int row = m0 + lg * 4 + i;
        const int bidx = row >> 10, nn = row & 1023;
        Qb[(((bidx * 8 + hh) * 1024) + nn) * 32 + d] = f2bf((acc[i] + bb) * QSCALE);
      }
    } else {
      #pragma unroll
      for (int i = 0; i < 4; ++i) {
        const int row = m0 + lg * 4 + i;
        const int bidx = row >> 10, nn = row & 1023;
        Kb[(((bidx * 8 + hh) * 1024) + nn) * 32 + d] = f2bf(acc[i] + bb);
      }
    }
  }
}

// ---------------- fused masked attention --------------------------------------
// grid 1024: b = bi&7 (XCD-affine), hp = (bi>>3)&1, q0 = (bi>>4)*16.
// block 512 = 8 waves: head = hp*4 + (w&3), key-half = w>>2 (512 keys, 8 iters).
// S^T (q in lanes) + O^T (O cols = q). Fixed-max softmax: p = exp2(s + bias),
// masked -> exact 0 -> partial (o, l) over key-halves sum exactly; combined
// through an LDS overlay (aliases the dead P buffers) with 2 barriers.
__global__ __launch_bounds__(512, 6) void k_attn(
    const unsigned short* __restrict__ Qb, const unsigned short* __restrict__ Kb,
    const unsigned short* __restrict__ Vt, const unsigned short* __restrict__ Bias,
    unsigned short* __restrict__ AO) {
  __shared__ alignas(16) unsigned char smem[36864];
  typedef unsigned short Pbuf[2][16][72];     // per-wave P: [buf][q][64 keys+pad]
  Pbuf* Pw = reinterpret_cast<Pbuf*>(smem);   // Pw[w][buf][q][key]
  typedef float Obuf[64][13];                 // combine overlay (stride 13: conflict-free)
  Obuf* OB = reinterpret_cast<Obuf*>(smem);   // OB[hl][lane][slot]

  const int lane = threadIdx.x & 63;
  const int w = threadIdx.x >> 6;
  const int hl = w & 3, half = w >> 2;
  const int lr = lane & 15, lg = lane >> 4;
  const int bi = blockIdx.x;
  const int b = bi & 7;                       // XCD affinity: batch b -> XCD b
  const int hp = (bi >> 3) & 1;
  const int q0 = (bi >> 4) << 4;
  const int h = hp * 4 + hl;

  const unsigned short* Qh = Qb + (size_t)((b * 8 + h) * 1024) * 32;
  const unsigned short* Kh = Kb + (size_t)((b * 8 + h) * 1024) * 32
                             + (half << 9) * 32 + lr * 32 + lg * 8;
  const unsigned short* Vh = Vt + (size_t)((b * 8 + h) * 32) * 1024
                             + lr * 1024 + (half << 9) + lg * 8;
  const unsigned short* Brow = Bias + ((size_t)b << 20) + (size_t)(q0 + lr) * 1024
                             + (half << 9) + lg * 4;

  const bf16x8 qf = ldfrag(Qh + (q0 + lr) * 32 + lg * 8);

  f32x4 o0 = {0.f, 0.f, 0.f, 0.f}, o1 = {0.f, 0.f, 0.f, 0.f};
  f32x4 ps = {0.f, 0.f, 0.f, 0.f};            // 4 parallel psum accumulators
  bf16x8 vprev0[2], vprev1[2];                // V(t-1) fragments for lagged PV

  for (int t = 0; t < 8; ++t) {
    const int k0 = t << 6;                    // offset within this key-half

    // ---- loads for tile t ----
    bf16x8 kf[4];
    #pragma unroll
    for (int st = 0; st < 4; ++st)
      kf[st] = ldfrag(Kh + (k0 + st * 16) * 32);
    bf16x8 vc00 = ldfrag(Vh + k0);
    bf16x8 vc01 = ldfrag(Vh + k0 + 32);
    bf16x8 vc10 = ldfrag(Vh + 16 * 1024 + k0);
    bf16x8 vc11 = ldfrag(Vh + 16 * 1024 + k0 + 32);
    ushort4 bb[4];
    #pragma unroll
    for (int st = 0; st < 4; ++st)
      bb[st] = *reinterpret_cast<const ushort4*>(Brow + k0 + st * 16);

    // ---- QK^T: s[st] rows = keys k0+st*16+lg*4+i, cols = q (lane lr) ----
    const f32x4 zz = {0.f, 0.f, 0.f, 0.f};
    f32x4 s[4];
    #pragma unroll
    for (int st = 0; st < 4; ++st)
      s[st] = mfma16(kf[st], qf, zz);

    // ---- read P(t-1) early; completes under the exp/pack below ----
    bf16x8 pf0, pf1;
    if (t > 0) {
      const unsigned short* pb = &Pw[w][(t - 1) & 1][lr][0];
      pf0 = *reinterpret_cast<const bf16x8*>(pb + lg * 8);
      pf1 = *reinterpret_cast<const bf16x8*>(pb + 32 + lg * 8);
    }

    // ---- p = exp2(s + bias); masked bias = -60000 -> exp2 underflows to 0 ----
    float p[4][4];
    #pragma unroll
    for (int st = 0; st < 4; ++st) {
      const unsigned short* bp = (const unsigned short*)&bb[st];
      #pragma unroll
      for (int i = 0; i < 4; ++i) {
        p[st][i] = exp2f(s[st][i] + h2f(bp[i]));
        ps[st] += p[st][i];
      }
    }

    // ---- pack P(t) -> LDS buf[t&1] ----
    #pragma unroll
    for (int st = 0; st < 4; ++st) {
      bf16x4 pw;
      #pragma unroll
      for (int i = 0; i < 4; ++i) pw[i] = (__bf16)p[st][i];
      *reinterpret_cast<bf16x4*>(&Pw[w][t & 1][lr][st * 16 + lg * 4]) = pw;
    }

    // ---- PV(t-1) with V(t-1) ----
    if (t > 0) {
      o0 = mfma16(vprev0[0], pf0, o0);
      o0 = mfma16(vprev0[1], pf1, o0);
      o1 = mfma16(vprev1[0], pf0, o1);
      o1 = mfma16(vprev1[1], pf1, o1);
    }
    vprev0[0] = vc00; vprev0[1] = vc01;
    vprev1[0] = vc10; vprev1[1] = vc11;
  }

  // epilogue: PV(7) (buf index 7&1 = 1)
  {
    const unsigned short* pb = &Pw[w][1][lr][0];
    const bf16x8 pf0 = *reinterpret_cast<const bf16x8*>(pb + lg * 8);
    const bf16x8 pf1 = *reinterpret_cast<const bf16x8*>(pb + 32 + lg * 8);
    o0 = mfma16(vprev0[0], pf0, o0);
    o0 = mfma16(vprev0[1], pf1, o0);
    o1 = mfma16(vprev1[0], pf0, o1);
    o1 = mfma16(vprev1[1], pf1, o1);
  }

  float psum = ps[0] + ps[1] + ps[2] + ps[3];

  // ---- combine key-halves: half=1 publishes partials, half=0 finishes ----
  __syncthreads();                            // all P reads done (OB aliases P)
  if (half == 1) {
    #pragma unroll
    for (int i = 0; i < 4; ++i) {
      OB[hl][lane][i] = o0[i];
      OB[hl][lane][4 + i] = o1[i];
    }
    OB[hl][lane][8] = psum;
  }
  __syncthreads();
  if (half == 0) {
    #pragma unroll
    for (int i = 0; i < 4; ++i) {
      o0[i] += OB[hl][lane][i];
      o1[i] += OB[hl][lane][4 + i];
    }
    psum += OB[hl][lane][8];
    psum += __shfl_xor(psum, 16);
    psum += __shfl_xor(psum, 32);
    const float linv = 1.0f / psum;           // per-lane (q = lr)

    ushort4 r0, r1;
    unsigned short* r0p = (unsigned short*)&r0;
    unsigned short* r1p = (unsigned short*)&r1;
    #pragma unroll
    for (int i = 0; i < 4; ++i) {
      r0p[i] = f2bf(o0[i] * linv);
      r1p[i] = f2bf(o1[i] * linv);
    }
    const int row = (b << 10) + q0 + lr;
    *reinterpret_cast<ushort4*>(&AO[row * 256 + h * 32 + lg * 4]) = r0;
    *reinterpret_cast<ushort4*>(&AO[row * 256 + h * 32 + 16 + lg * 4]) = r1;
  }
}

// ---------------- output projection -------------------------------------------
// grid (512, 2): x = m-tile of 16, y = 128-col half.
__global__ __launch_bounds__(256, 2) void k_oproj(
    const unsigned short* __restrict__ AO, const unsigned short* __restrict__ Wto,
    const float* __restrict__ bo, float* __restrict__ out) {
  const int lane = threadIdx.x & 63;
  const int w = threadIdx.x >> 6;
  const int lr = lane & 15, lg = lane >> 4;
  const int m0 = blockIdx.x << 4;

  bf16x8 a[8];
  #pragma unroll
  for (int ks = 0; ks < 8; ++ks)
    a[ks] = ldfrag(AO + (m0 + lr) * 256 + ks * 32 + lg * 8);

  #pragma unroll
  for (int j = 0; j < 2; ++j) {
    const int c0 = (blockIdx.y * 2 + j) * 64 + w * 16;
    bf16x8 bfr[8];
    #pragma unroll
    for (int ks = 0; ks < 8; ++ks)
      bfr[ks] = ldfrag(Wto + (c0 + lr) * 256 + ks * 32 + lg * 8);
    f32x4 acc = {0.f, 0.f, 0.f, 0.f};
    #pragma unroll
    for (int ks = 0; ks < 8; ++ks)
      acc = mfma16(a[ks], bfr[ks], acc);
    const float bb = bo[c0 + lr];
    #pragma unroll
    for (int i = 0; i < 4; ++i) {
      const int row = m0 + lg * 4 + i;
      out[row * 256 + c0 + lr] = acc[i] + bb;
    }
  }
}

extern "C" void kernel_launch(void* const* d_in, const int* in_sizes, int n_in,
                              void* d_out, int out_size, void* d_ws, size_t ws_size,
                              hipStream_t stream) {
  const float* X   = (const float*)d_in[0];
  const int*   A   = (const int*)d_in[1];
  const float* D   = (const float*)d_in[2];
  const float* Wq  = (const float*)d_in[3];
  const float* bq  = (const float*)d_in[4];
  const float* Wk  = (const float*)d_in[5];
  const float* bk  = (const float*)d_in[6];
  const float* Wv  = (const float*)d_in[7];
  const float* bv  = (const float*)d_in[8];
  const float* Wo  = (const float*)d_in[9];
  const float* bo  = (const float*)d_in[10];
  const float* dsc = (const float*)d_in[11];
  float* out = (float*)d_out;

  unsigned short* ws = (unsigned short*)d_ws;
  unsigned short* Xbf  = ws;                   // 2,097,152  (reused as AO later)
  unsigned short* Wt   = ws + 2097152;         //   262,144
  unsigned short* Qb   = ws + 2359296;         // 2,097,152
  unsigned short* Kb   = ws + 4456448;         // 2,097,152
  unsigned short* Vt   = ws + 6553600;         // 2,097,152
  unsigned short* Bias = ws + 8650752;         // 8,388,608  (total ~34.1 MB)
  unsigned short* AO   = Xbf;                  // alias: Xbf dead after k_qkv

  hipLaunchKernelGGL(k_prep, dim3(11264), dim3(256), 0, stream,
                     X, A, D, dsc, Wq, Wk, Wv, Wo, Xbf, Wt, Bias);
  hipLaunchKernelGGL(k_qkv, dim3(512, 3), dim3(256), 0, stream,
                     Xbf, Wt, bq, bk, bv, Qb, Kb, Vt);
  hipLaunchKernelGGL(k_attn, dim3(1024), dim3(512), 0, stream,
                     Qb, Kb, Vt, Bias, AO);
  hipLaunchKernelGGL(k_oproj, dim3(512, 2), dim3(256), 0, stream,
                     AO, Wt + 196608, bo, out);
}

// Round 10
// 99.942 us; speedup vs baseline: 2.1321x; 1.3781x over previous
//
#include <hip/hip_runtime.h>

// MultiHeadGraphAttention: B=8, N=1024, IN=OUT=256, H=8, d_k=32
// prep(cvt + fused mask/dist bias fp16) -> QKV gemm (W-stationary bf16 MFMA)
// -> fused masked attention: K/V resident in LDS per (b,h,q-quarter) block
//    (XOR-swizzled, bank-uniform), S^T through LDS in fp16, bias added in
//    B-fragment layout (ushort8 loads), fixed-max exp2 softmax -> out proj.

typedef __bf16 bf16x8 __attribute__((ext_vector_type(8)));
typedef float f32x4 __attribute__((ext_vector_type(4)));
typedef int i32x4 __attribute__((ext_vector_type(4)));
typedef unsigned short u16x8 __attribute__((ext_vector_type(8)));
typedef _Float16 f16x8 __attribute__((ext_vector_type(8)));

#define DEV static __device__ __forceinline__

#define LOG2E 1.4426950408889634f
#define QSCALE 0.2550351062f   // (1/sqrt(32)) * log2(e)

DEV unsigned short f2bf(float f) {   // RNE f32 -> bf16 bits
  union { float f; unsigned u; } x; x.f = f;
  unsigned r = x.u + 0x7fffu + ((x.u >> 16) & 1u);
  return (unsigned short)(r >> 16);
}

DEV unsigned short f2h(float f) {    // f32 -> fp16 bits (RNE)
  _Float16 h = (_Float16)f;
  unsigned short u;
  __builtin_memcpy(&u, &h, 2);
  return u;
}

DEV float h2f(unsigned short u) {    // fp16 bits -> f32
  _Float16 h;
  __builtin_memcpy(&h, &u, 2);
  return (float)h;
}

DEV f32x4 mfma16(bf16x8 a, bf16x8 b, f32x4 c) {
  return __builtin_amdgcn_mfma_f32_16x16x32_bf16(a, b, c, 0, 0, 0);
}

DEV bf16x8 ldfrag(const unsigned short* p) {
  return *reinterpret_cast<const bf16x8*>(p);
}

// ---------------- prep ---------------------------------------------------------
// range 0: Bias[b][q][k] fp16 = A<=0 ? -60000 : -ds*log2e*D   (4 elems/thread)
// range 1: X f32 -> bf16 ; range 2: W -> bf16 transposed [n][k]
__global__ __launch_bounds__(256) void k_prep(
    const float* __restrict__ X, const int* __restrict__ A,
    const float* __restrict__ D, const float* __restrict__ dscale,
    const float* __restrict__ Wq, const float* __restrict__ Wk,
    const float* __restrict__ Wv, const float* __restrict__ Wo,
    unsigned short* __restrict__ Xbf, unsigned short* __restrict__ Wt,
    unsigned short* __restrict__ Bias) {
  const int tid = blockIdx.x * 256 + threadIdx.x;
  const int NB4 = (8 * 1024 * 1024) / 4;      // 2,097,152 bias quads
  const int NX4 = (8192 * 256) / 4;           //   524,288 X quads
  if (tid < NB4) {
    const i32x4 a4 = reinterpret_cast<const i32x4*>(A)[tid];
    const f32x4 d4 = reinterpret_cast<const f32x4*>(D)[tid];
    const float c = -dscale[0] * LOG2E;
    ushort4 o;
    unsigned short* op = (unsigned short*)&o;
    #pragma unroll
    for (int i = 0; i < 4; ++i)
      op[i] = f2h(a4[i] <= 0 ? -60000.0f : c * d4[i]);
    reinterpret_cast<ushort4*>(Bias)[tid] = o;
  } else if (tid < NB4 + NX4) {
    const int t = tid - NB4;
    float4 v = reinterpret_cast<const float4*>(X)[t];
    ushort4 o;
    o.x = f2bf(v.x); o.y = f2bf(v.y); o.z = f2bf(v.z); o.w = f2bf(v.w);
    reinterpret_cast<ushort4*>(Xbf)[t] = o;
  } else {
    int t = tid - NB4 - NX4;                  // 0 .. 262143
    int mat = t >> 16;
    int e = t & 65535;
    int n = e >> 8, k = e & 255;              // output Wt[mat][n][k]
    const float* W = (mat == 0) ? Wq : (mat == 1) ? Wk : (mat == 2) ? Wv : Wo;
    Wt[t] = f2bf(W[k * 256 + n]);
  }
}

// ---------------- QKV projection GEMM (W-stationary) ---------------------------
// grid (32, 12): x = 256-row m-chunk (16 m-tiles), y = mat*4 + col-slab.
// block 256 (4 waves); wave w owns 16 cols; its W fragments stay in registers
// across all 16 m-tiles -> W L2 traffic 196 MB -> 12 MB.
__global__ __launch_bounds__(256, 2) void k_qkv(
    const unsigned short* __restrict__ Xbf, const unsigned short* __restrict__ Wt,
    const float* __restrict__ bq, const float* __restrict__ bk,
    const float* __restrict__ bv,
    unsigned short* __restrict__ Qb, unsigned short* __restrict__ Kb,
    unsigned short* __restrict__ Vt) {
  const int lane = threadIdx.x & 63;
  const int w = threadIdx.x >> 6;
  const int lr = lane & 15, lg = lane >> 4;
  const int mat = blockIdx.y >> 2;
  const int nloc = (blockIdx.y & 3) * 64 + w * 16;
  const int mbase = blockIdx.x << 8;

  const unsigned short* Wm = Wt + mat * 65536;
  const float* bias = (mat == 0) ? bq : (mat == 1) ? bk : bv;

  bf16x8 bfr[8];
  #pragma unroll
  for (int ks = 0; ks < 8; ++ks)
    bfr[ks] = ldfrag(Wm + (nloc + lr) * 256 + ks * 32 + lg * 8);
  const float bb = bias[nloc + lr];
  const int cm = nloc + lr;
  const int hh = cm >> 5, d = cm & 31;

  for (int mt = 0; mt < 16; ++mt) {
    const int m0 = mbase + mt * 16;
    bf16x8 a[8];
    #pragma unroll
    for (int ks = 0; ks < 8; ++ks)
      a[ks] = ldfrag(Xbf + (m0 + lr) * 256 + ks * 32 + lg * 8);
    f32x4 acc = {0.f, 0.f, 0.f, 0.f};
    #pragma unroll
    for (int ks = 0; ks < 8; ++ks)
      acc = mfma16(a[ks], bfr[ks], acc);

    if (mat == 2) {                           // V transposed: 4 consecutive halfs
      ushort4 vv;
      unsigned short* vp = (unsigned short*)&vv;
      #pragma unroll
      for (int i = 0; i < 4; ++i) vp[i] = f2bf(acc[i] + bb);
      const int row = m0 + lg * 4;
      const int bidx = row >> 10, nn = row & 1023;
      *reinterpret_cast<ushort4*>(&Vt[(((bidx * 8 + hh) * 32) + d) * 1024 + nn]) = vv;
    } else if (mat == 0) {
      #pragma unroll
      for (int i = 0; i < 4; ++i) {
        const int row = m0 + lg * 4 + i;
        const int bidx = row >> 10, nn = row & 1023;
        Qb[(((bidx * 8 + hh) * 1024) + nn) * 32 + d] = f2bf((acc[i] + bb) * QSCALE);
      }
    } else {
      #pragma unroll
      for (int i = 0; i < 4; ++i) {
        const int row = m0 + lg * 4 + i;
        const int bidx = row >> 10, nn = row & 1023;
        Kb[(((bidx * 8 + hh) * 1024) + nn) * 32 + d] = f2bf(acc[i] + bb);
      }
    }
  }
}

// ---------------- fused masked attention --------------------------------------
// grid 256 = (b,h,q-quarter), bi = (h*4+qq)*8 + b  (XCD-affine: batch b -> XCD b;
// batch working set ~3.5 MB fits the 4 MB per-XCD L2). 1 block/CU.
// block 512 = 8 waves; wave w owns 32 q-rows (2 subtiles of 16).
// K (64KB) + V^T (64KB) staged in LDS once, XOR-swizzled (bank-uniform);
// S^T goes through per-wave LDS in fp16; bias (fp16) is added AFTER the
// transpose where a contiguous ushort8 load matches the fragment layout.
// Fixed-max softmax: p = exp2(s + bias), masked -> exact 0.
__global__ __launch_bounds__(512, 2) void k_attn(
    const unsigned short* __restrict__ Qb, const unsigned short* __restrict__ Kb,
    const unsigned short* __restrict__ Vt, const unsigned short* __restrict__ Bias,
    unsigned short* __restrict__ AO) {
  __shared__ alignas(16) unsigned short Klds[1024 * 32];  // 64KB, seg^=row&3
  __shared__ alignas(16) unsigned short Vlds[32 * 1024];  // 64KB, chunk^=row&7
  __shared__ alignas(16) unsigned short Sbuf[8][16][72];  // 18KB per-wave S^T

  const int tid = threadIdx.x;
  const int lane = tid & 63;
  const int w = tid >> 6;
  const int lr = lane & 15, lg = lane >> 4;
  const int bi = blockIdx.x;
  const int b = bi & 7;                       // XCD affinity
  const int j = bi >> 3;
  const int h = j >> 2, qq = j & 3;
  const int q0w = qq * 256 + w * 32;

  const unsigned short* Kg = Kb + ((size_t)(b * 8 + h) << 15);
  const unsigned short* Vg = Vt + ((size_t)(b * 8 + h) << 15);
  const unsigned short* Qh = Qb + ((size_t)(b * 8 + h) << 15);

  // ---- stage K: linear global 16B/thread -> swizzled LDS ----
  #pragma unroll
  for (int p = 0; p < 8; ++p) {
    const int c = tid + p * 512;              // 16B chunk id, 4096 total
    const int row = c >> 2, seg = c & 3;
    const u16x8 v = *reinterpret_cast<const u16x8*>(Kg + c * 8);
    *reinterpret_cast<u16x8*>(&Klds[row * 32 + ((seg ^ (row & 3)) << 3)]) = v;
  }
  // ---- stage V^T: linear global -> swizzled LDS ----
  #pragma unroll
  for (int p = 0; p < 8; ++p) {
    const int c = tid + p * 512;              // 16B chunk id, 4096 total
    const int row = c >> 7, ch = c & 127;
    const u16x8 v = *reinterpret_cast<const u16x8*>(Vg + c * 8);
    *reinterpret_cast<u16x8*>(&Vlds[row * 1024 + ((ch ^ (row & 7)) << 3)]) = v;
  }

  // Q fragments for the wave's 2 subtiles, bias base pointers
  bf16x8 qf[2];
  qf[0] = ldfrag(Qh + (q0w + lr) * 32 + lg * 8);
  qf[1] = ldfrag(Qh + (q0w + 16 + lr) * 32 + lg * 8);
  const unsigned short* Br0 = Bias + ((size_t)b << 20) + (size_t)(q0w + lr) * 1024;
  const unsigned short* Br1 = Br0 + (size_t)16 * 1024;

  // bias prefetch for tile 0: [sub][frag], frag = 32-key half
  u16x8 bc[2][2], bn[2][2];
  #pragma unroll
  for (int fr = 0; fr < 2; ++fr) {
    bc[0][fr] = *reinterpret_cast<const u16x8*>(Br0 + fr * 32 + lg * 8);
    bc[1][fr] = *reinterpret_cast<const u16x8*>(Br1 + fr * 32 + lg * 8);
  }

  __syncthreads();

  f32x4 o[2][2];                              // [sub][dh]
  #pragma unroll
  for (int s = 0; s < 2; ++s)
    #pragma unroll
    for (int dh = 0; dh < 2; ++dh) o[s][dh] = f32x4{0.f, 0.f, 0.f, 0.f};
  float ps[2] = {0.f, 0.f};

  for (int t = 0; t < 16; ++t) {
    const int k0 = t << 6;
    if (t < 15) {                             // bias(t+1) prefetch (HBM stream)
      #pragma unroll
      for (int fr = 0; fr < 2; ++fr) {
        bn[0][fr] = *reinterpret_cast<const u16x8*>(Br0 + k0 + 64 + fr * 32 + lg * 8);
        bn[1][fr] = *reinterpret_cast<const u16x8*>(Br1 + k0 + 64 + fr * 32 + lg * 8);
      }
    }

    // K fragments from LDS (seg XOR swizzle)
    bf16x8 kf[4];
    #pragma unroll
    for (int st = 0; st < 4; ++st) {
      const int row = k0 + st * 16 + lr;
      kf[st] = *reinterpret_cast<const bf16x8*>(
          &Klds[row * 32 + ((lg ^ (lr & 3)) << 3)]);
    }
    // V^T fragments from LDS (chunk XOR swizzle); shared by both subtiles
    bf16x8 vf[2][2];
    #pragma unroll
    for (int dh = 0; dh < 2; ++dh)
      #pragma unroll
      for (int fr = 0; fr < 2; ++fr) {
        const int row = dh * 16 + lr;
        const int ch = t * 8 + ((fr * 4 + lg) ^ (lr & 7));
        vf[dh][fr] = *reinterpret_cast<const bf16x8*>(&Vlds[row * 1024 + ch * 8]);
      }

    #pragma unroll
    for (int s = 0; s < 2; ++s) {
      // QK^T: s-layout (keys in regs, q in lanes)
      const f32x4 zz = {0.f, 0.f, 0.f, 0.f};
      f32x4 sv[4];
      #pragma unroll
      for (int st = 0; st < 4; ++st)
        sv[st] = mfma16(kf[st], qf[s], zz);

      // S^T -> LDS as fp16 (8B per st)
      #pragma unroll
      for (int st = 0; st < 4; ++st) {
        ushort4 sw;
        unsigned short* sp = (unsigned short*)&sw;
        #pragma unroll
        for (int i = 0; i < 4; ++i) sp[i] = f2h(sv[st][i]);
        *reinterpret_cast<ushort4*>(&Sbuf[w][lr][st * 16 + lg * 4]) = sw;
      }

      // read back in B-fragment layout: lane (q=lr, lg) holds keys lg*8..+7
      #pragma unroll
      for (int fr = 0; fr < 2; ++fr) {
        const f16x8 sf = *reinterpret_cast<const f16x8*>(&Sbuf[w][lr][fr * 32 + lg * 8]);
        const unsigned short* bp = (const unsigned short*)&bc[s][fr];
        float p8[8];
        float psl = 0.f;
        #pragma unroll
        for (int i = 0; i < 8; ++i) {
          p8[i] = exp2f((float)sf[i] + h2f(bp[i]));
          psl += p8[i];
        }
        ps[s] += psl;
        bf16x8 pf;
        #pragma unroll
        for (int i = 0; i < 8; ++i) pf[i] = (__bf16)p8[i];
        o[s][0] = mfma16(vf[0][fr], pf, o[s][0]);
        o[s][1] = mfma16(vf[1][fr], pf, o[s][1]);
      }
    }

    #pragma unroll
    for (int s = 0; s < 2; ++s)
      #pragma unroll
      for (int fr = 0; fr < 2; ++fr)
        bc[s][fr] = bn[s][fr];
  }

  // epilogue: reduce psum over the 4 lg lanes of each q, normalize, store
  #pragma unroll
  for (int s = 0; s < 2; ++s) {
    float psum = ps[s];
    psum += __shfl_xor(psum, 16);
    psum += __shfl_xor(psum, 32);
    const float linv = 1.0f / psum;
    ushort4 r0, r1;
    unsigned short* r0p = (unsigned short*)&r0;
    unsigned short* r1p = (unsigned short*)&r1;
    #pragma unroll
    for (int i = 0; i < 4; ++i) {
      r0p[i] = f2bf(o[s][0][i] * linv);
      r1p[i] = f2bf(o[s][1][i] * linv);
    }
    const int row = (b << 10) + q0w + s * 16 + lr;
    *reinterpret_cast<ushort4*>(&AO[row * 256 + h * 32 + lg * 4]) = r0;
    *reinterpret_cast<ushort4*>(&AO[row * 256 + h * 32 + 16 + lg * 4]) = r1;
  }
}

// ---------------- output projection (W-stationary) -----------------------------
// grid (64, 4): x = 128-row m-chunk (8 m-tiles), y = col-slab of 64.
__global__ __launch_bounds__(256, 2) void k_oproj(
    const unsigned short* __restrict__ AO, const unsigned short* __restrict__ Wto,
    const float* __restrict__ bo, float* __restrict__ out) {
  const int lane = threadIdx.x & 63;
  const int w = threadIdx.x >> 6;
  const int lr = lane & 15, lg = lane >> 4;
  const int c0 = blockIdx.y * 64 + w * 16;
  const int mbase = blockIdx.x << 7;

  bf16x8 bfr[8];
  #pragma unroll
  for (int ks = 0; ks < 8; ++ks)
    bfr[ks] = ldfrag(Wto + (c0 + lr) * 256 + ks * 32 + lg * 8);
  const float bb = bo[c0 + lr];

  for (int mt = 0; mt < 8; ++mt) {
    const int m0 = mbase + mt * 16;
    bf16x8 a[8];
    #pragma unroll
    for (int ks = 0; ks < 8; ++ks)
      a[ks] = ldfrag(AO + (m0 + lr) * 256 + ks * 32 + lg * 8);
    f32x4 acc = {0.f, 0.f, 0.f, 0.f};
    #pragma unroll
    for (int ks = 0; ks < 8; ++ks)
      acc = mfma16(a[ks], bfr[ks], acc);
    #pragma unroll
    for (int i = 0; i < 4; ++i) {
      const int row = m0 + lg * 4 + i;
      out[row * 256 + c0 + lr] = acc[i] + bb;
    }
  }
}

extern "C" void kernel_launch(void* const* d_in, const int* in_sizes, int n_in,
                              void* d_out, int out_size, void* d_ws, size_t ws_size,
                              hipStream_t stream) {
  const float* X   = (const float*)d_in[0];
  const int*   A   = (const int*)d_in[1];
  const float* D   = (const float*)d_in[2];
  const float* Wq  = (const float*)d_in[3];
  const float* bq  = (const float*)d_in[4];
  const float* Wk  = (const float*)d_in[5];
  const float* bk  = (const float*)d_in[6];
  const float* Wv  = (const float*)d_in[7];
  const float* bv  = (const float*)d_in[8];
  const float* Wo  = (const float*)d_in[9];
  const float* bo  = (const float*)d_in[10];
  const float* dsc = (const float*)d_in[11];
  float* out = (float*)d_out;

  unsigned short* ws = (unsigned short*)d_ws;
  unsigned short* Xbf  = ws;                   // 2,097,152  (reused as AO later)
  unsigned short* Wt   = ws + 2097152;         //   262,144
  unsigned short* Qb   = ws + 2359296;         // 2,097,152
  unsigned short* Kb   = ws + 4456448;         // 2,097,152
  unsigned short* Vt   = ws + 6553600;         // 2,097,152
  unsigned short* Bias = ws + 8650752;         // 8,388,608  (total ~34.1 MB)
  unsigned short* AO   = Xbf;                  // alias: Xbf dead after k_qkv

  hipLaunchKernelGGL(k_prep, dim3(11264), dim3(256), 0, stream,
                     X, A, D, dsc, Wq, Wk, Wv, Wo, Xbf, Wt, Bias);
  hipLaunchKernelGGL(k_qkv, dim3(32, 12), dim3(256), 0, stream,
                     Xbf, Wt, bq, bk, bv, Qb, Kb, Vt);
  hipLaunchKernelGGL(k_attn, dim3(256), dim3(512), 0, stream,
                     Qb, Kb, Vt, Bias, AO);
  hipLaunchKernelGGL(k_oproj, dim3(64, 4), dim3(256), 0, stream,
                     AO, Wt + 196608, bo, out);
}

// Round 12
// 88.913 us; speedup vs baseline: 2.3966x; 1.1240x over previous
//
#include <hip/hip_runtime.h>

// MultiHeadGraphAttention: B=8, N=1024, IN=OUT=256, H=8, d_k=32
// All-fp16 pipeline. prep(cvt + fused mask/dist bias fp16) -> QKV gemm
// (f16 MFMA, W-stationary, Q pre-scaled) -> fused masked attention:
// K/V resident in LDS (XOR-swizzled), S^T through LDS fp16, packed-f16 bias
// add, fixed-max exp2 softmax, l via ones-MFMA -> out proj.

typedef _Float16 f16x8 __attribute__((ext_vector_type(8)));
typedef __fp16 h16x2 __attribute__((ext_vector_type(2)));   // cvt_pkrtz result type
typedef float f32x4 __attribute__((ext_vector_type(4)));
typedef int i32x4 __attribute__((ext_vector_type(4)));
typedef unsigned short u16x8 __attribute__((ext_vector_type(8)));

#define DEV static __device__ __forceinline__

#define LOG2E 1.4426950408889634f
#define QSCALE 0.2550351062f   // (1/sqrt(32)) * log2(e)

DEV unsigned short f2h(float f) {    // f32 -> fp16 bits (RNE)
  _Float16 h = (_Float16)f;
  unsigned short u;
  __builtin_memcpy(&u, &h, 2);
  return u;
}

DEV f32x4 mfma16h(f16x8 a, f16x8 b, f32x4 c) {
  return __builtin_amdgcn_mfma_f32_16x16x32_f16(a, b, c, 0, 0, 0);
}

DEV f16x8 ldfragh(const unsigned short* p) {
  return *reinterpret_cast<const f16x8*>(p);
}

// ---------------- prep ---------------------------------------------------------
// range 0: Bias[b][q][k] fp16 = A<=0 ? -60000 : -ds*log2e*D   (4 elems/thread)
// range 1: X f32 -> f16 ; range 2: W -> f16 transposed [n][k]
__global__ __launch_bounds__(256) void k_prep(
    const float* __restrict__ X, const int* __restrict__ A,
    const float* __restrict__ D, const float* __restrict__ dscale,
    const float* __restrict__ Wq, const float* __restrict__ Wk,
    const float* __restrict__ Wv, const float* __restrict__ Wo,
    unsigned short* __restrict__ Xh, unsigned short* __restrict__ Wt,
    unsigned short* __restrict__ Bias) {
  const int tid = blockIdx.x * 256 + threadIdx.x;
  const int NB4 = (8 * 1024 * 1024) / 4;      // 2,097,152 bias quads
  const int NX4 = (8192 * 256) / 4;           //   524,288 X quads
  if (tid < NB4) {
    const i32x4 a4 = reinterpret_cast<const i32x4*>(A)[tid];
    const f32x4 d4 = reinterpret_cast<const f32x4*>(D)[tid];
    const float c = -dscale[0] * LOG2E;
    ushort4 o;
    unsigned short* op = (unsigned short*)&o;
    #pragma unroll
    for (int i = 0; i < 4; ++i)
      op[i] = f2h(a4[i] <= 0 ? -60000.0f : c * d4[i]);
    reinterpret_cast<ushort4*>(Bias)[tid] = o;
  } else if (tid < NB4 + NX4) {
    const int t = tid - NB4;
    float4 v = reinterpret_cast<const float4*>(X)[t];
    union { h16x2 h2[2]; ushort4 u; } o;
    o.h2[0] = __builtin_amdgcn_cvt_pkrtz(v.x, v.y);
    o.h2[1] = __builtin_amdgcn_cvt_pkrtz(v.z, v.w);
    reinterpret_cast<ushort4*>(Xh)[t] = o.u;
  } else {
    int t = tid - NB4 - NX4;                  // 0 .. 262143
    int mat = t >> 16;
    int e = t & 65535;
    int n = e >> 8, k = e & 255;              // output Wt[mat][n][k]
    const float* W = (mat == 0) ? Wq : (mat == 1) ? Wk : (mat == 2) ? Wv : Wo;
    Wt[t] = f2h(W[k * 256 + n]);
  }
}

// ---------------- QKV projection GEMM (W-stationary, f16) ----------------------
// grid (32, 12): x = 256-row m-chunk (16 m-tiles), y = mat*4 + col-slab.
__global__ __launch_bounds__(256, 2) void k_qkv(
    const unsigned short* __restrict__ Xh, const unsigned short* __restrict__ Wt,
    const float* __restrict__ bq, const float* __restrict__ bk,
    const float* __restrict__ bv,
    unsigned short* __restrict__ Qb, unsigned short* __restrict__ Kb,
    unsigned short* __restrict__ Vt) {
  const int lane = threadIdx.x & 63;
  const int w = threadIdx.x >> 6;
  const int lr = lane & 15, lg = lane >> 4;
  const int mat = blockIdx.y >> 2;
  const int nloc = (blockIdx.y & 3) * 64 + w * 16;
  const int mbase = blockIdx.x << 8;

  const unsigned short* Wm = Wt + mat * 65536;
  const float* bias = (mat == 0) ? bq : (mat == 1) ? bk : bv;

  f16x8 bfr[8];
  #pragma unroll
  for (int ks = 0; ks < 8; ++ks)
    bfr[ks] = ldfragh(Wm + (nloc + lr) * 256 + ks * 32 + lg * 8);
  const float bb = bias[nloc + lr];
  const int cm = nloc + lr;
  const int hh = cm >> 5, d = cm & 31;

  for (int mt = 0; mt < 16; ++mt) {
    const int m0 = mbase + mt * 16;
    f16x8 a[8];
    #pragma unroll
    for (int ks = 0; ks < 8; ++ks)
      a[ks] = ldfragh(Xh + (m0 + lr) * 256 + ks * 32 + lg * 8);
    f32x4 acc = {0.f, 0.f, 0.f, 0.f};
    #pragma unroll
    for (int ks = 0; ks < 8; ++ks)
      acc = mfma16h(a[ks], bfr[ks], acc);

    if (mat == 2) {                           // V transposed: 4 consecutive halfs
      union { h16x2 h2[2]; ushort4 u; } vv;
      vv.h2[0] = __builtin_amdgcn_cvt_pkrtz(acc[0] + bb, acc[1] + bb);
      vv.h2[1] = __builtin_amdgcn_cvt_pkrtz(acc[2] + bb, acc[3] + bb);
      const int row = m0 + lg * 4;
      const int bidx = row >> 10, nn = row & 1023;
      *reinterpret_cast<ushort4*>(&Vt[(((bidx * 8 + hh) * 32) + d) * 1024 + nn]) = vv.u;
    } else if (mat == 0) {
      #pragma unroll
      for (int i = 0; i < 4; ++i) {
        const int row = m0 + lg * 4 + i;
        const int bidx = row >> 10, nn = row & 1023;
        Qb[(((bidx * 8 + hh) * 1024) + nn) * 32 + d] = f2h((acc[i] + bb) * QSCALE);
      }
    } else {
      #pragma unroll
      for (int i = 0; i < 4; ++i) {
        const int row = m0 + lg * 4 + i;
        const int bidx = row >> 10, nn = row & 1023;
        Kb[(((bidx * 8 + hh) * 1024) + nn) * 32 + d] = f2h(acc[i] + bb);
      }
    }
  }
}

// ---------------- fused masked attention (all-f16) -----------------------------
// grid 256 = (b,h,q-quarter), bi = (h*4+qq)*8 + b  (XCD-affine). 1 block/CU.
// block 512 = 8 waves; wave w owns 32 q-rows (2 subtiles of 16).
// K (64KB) + V^T (64KB) staged in LDS once, XOR-swizzled; S^T through per-wave
// LDS fp16; bias added packed-f16 in B-fragment layout; p = exp2(s+bias)
// (fixed max 0, masked -> exact 0); l accumulated by ones-MFMA (no shuffles).
__global__ __launch_bounds__(512, 2) void k_attn(
    const unsigned short* __restrict__ Qb, const unsigned short* __restrict__ Kb,
    const unsigned short* __restrict__ Vt, const unsigned short* __restrict__ Bias,
    unsigned short* __restrict__ AO) {
  __shared__ alignas(16) unsigned short Klds[1024 * 32];  // 64KB, seg^=row&3
  __shared__ alignas(16) unsigned short Vlds[32 * 1024];  // 64KB, chunk^=row&7
  __shared__ alignas(16) unsigned short Sbuf[8][16][72];  // 18KB per-wave S^T

  const int tid = threadIdx.x;
  const int lane = tid & 63;
  const int w = tid >> 6;
  const int lr = lane & 15, lg = lane >> 4;
  const int bi = blockIdx.x;
  const int b = bi & 7;                       // XCD affinity
  const int j = bi >> 3;
  const int h = j >> 2, qq = j & 3;
  const int q0w = qq * 256 + w * 32;

  const unsigned short* Kg = Kb + ((size_t)(b * 8 + h) << 15);
  const unsigned short* Vg = Vt + ((size_t)(b * 8 + h) << 15);
  const unsigned short* Qh = Qb + ((size_t)(b * 8 + h) << 15);

  // ---- stage K: linear global 16B/thread -> swizzled LDS ----
  #pragma unroll
  for (int p = 0; p < 8; ++p) {
    const int c = tid + p * 512;              // 16B chunk id, 4096 total
    const int row = c >> 2, seg = c & 3;
    const u16x8 v = *reinterpret_cast<const u16x8*>(Kg + c * 8);
    *reinterpret_cast<u16x8*>(&Klds[row * 32 + ((seg ^ (row & 3)) << 3)]) = v;
  }
  // ---- stage V^T: linear global -> swizzled LDS ----
  #pragma unroll
  for (int p = 0; p < 8; ++p) {
    const int c = tid + p * 512;              // 16B chunk id, 4096 total
    const int row = c >> 7, ch = c & 127;
    const u16x8 v = *reinterpret_cast<const u16x8*>(Vg + c * 8);
    *reinterpret_cast<u16x8*>(&Vlds[row * 1024 + ((ch ^ (row & 7)) << 3)]) = v;
  }

  // Q fragments for the wave's 2 subtiles, bias base pointers
  f16x8 qf[2];
  qf[0] = ldfragh(Qh + (q0w + lr) * 32 + lg * 8);
  qf[1] = ldfragh(Qh + (q0w + 16 + lr) * 32 + lg * 8);
  const unsigned short* Br0 = Bias + ((size_t)b << 20) + (size_t)(q0w + lr) * 1024;
  const unsigned short* Br1 = Br0 + (size_t)16 * 1024;

  // bias prefetch for tile 0: [sub][frag], frag = 32-key half
  u16x8 bc[2][2], bn[2][2];
  #pragma unroll
  for (int fr = 0; fr < 2; ++fr) {
    bc[0][fr] = *reinterpret_cast<const u16x8*>(Br0 + fr * 32 + lg * 8);
    bc[1][fr] = *reinterpret_cast<const u16x8*>(Br1 + fr * 32 + lg * 8);
  }

  __syncthreads();

  f32x4 o[2][2];                              // [sub][dh]
  f32x4 lacc[2];                              // [sub] l accumulator (ones-MFMA)
  #pragma unroll
  for (int s = 0; s < 2; ++s) {
    #pragma unroll
    for (int dh = 0; dh < 2; ++dh) o[s][dh] = f32x4{0.f, 0.f, 0.f, 0.f};
    lacc[s] = f32x4{0.f, 0.f, 0.f, 0.f};
  }
  f16x8 onesv;
  #pragma unroll
  for (int i = 0; i < 8; ++i) onesv[i] = (_Float16)1.0f;

  for (int t = 0; t < 16; ++t) {
    const int k0 = t << 6;
    if (t < 15) {                             // bias(t+1) prefetch (HBM stream)
      #pragma unroll
      for (int fr = 0; fr < 2; ++fr) {
        bn[0][fr] = *reinterpret_cast<const u16x8*>(Br0 + k0 + 64 + fr * 32 + lg * 8);
        bn[1][fr] = *reinterpret_cast<const u16x8*>(Br1 + k0 + 64 + fr * 32 + lg * 8);
      }
    }

    // K fragments from LDS (seg XOR swizzle)
    f16x8 kf[4];
    #pragma unroll
    for (int st = 0; st < 4; ++st) {
      const int row = k0 + st * 16 + lr;
      kf[st] = *reinterpret_cast<const f16x8*>(
          &Klds[row * 32 + ((lg ^ (lr & 3)) << 3)]);
    }
    // V^T fragments from LDS (chunk XOR swizzle); shared by both subtiles
    f16x8 vf[2][2];
    #pragma unroll
    for (int dh = 0; dh < 2; ++dh)
      #pragma unroll
      for (int fr = 0; fr < 2; ++fr) {
        const int row = dh * 16 + lr;
        const int ch = t * 8 + ((fr * 4 + lg) ^ (lr & 7));
        vf[dh][fr] = *reinterpret_cast<const f16x8*>(&Vlds[row * 1024 + ch * 8]);
      }

    #pragma unroll
    for (int s = 0; s < 2; ++s) {
      // QK^T: S^T layout (keys in regs, q in lanes)
      const f32x4 zz = {0.f, 0.f, 0.f, 0.f};
      f32x4 sv[4];
      #pragma unroll
      for (int st = 0; st < 4; ++st)
        sv[st] = mfma16h(kf[st], qf[s], zz);

      // S^T -> LDS as fp16 via cvt_pkrtz (8B per subtile)
      #pragma unroll
      for (int st = 0; st < 4; ++st) {
        union { h16x2 h2[2]; ushort4 u; } sw;
        sw.h2[0] = __builtin_amdgcn_cvt_pkrtz(sv[st][0], sv[st][1]);
        sw.h2[1] = __builtin_amdgcn_cvt_pkrtz(sv[st][2], sv[st][3]);
        *reinterpret_cast<ushort4*>(&Sbuf[w][lr][st * 16 + lg * 4]) = sw.u;
      }

      // read back in B-fragment layout: lane (q=lr, lg) holds keys lg*8..+7
      #pragma unroll
      for (int fr = 0; fr < 2; ++fr) {
        const f16x8 sf = *reinterpret_cast<const f16x8*>(&Sbuf[w][lr][fr * 32 + lg * 8]);
        const f16x8 bfv = *reinterpret_cast<const f16x8*>(&bc[s][fr]);
        const f16x8 sb = sf + bfv;            // v_pk_add_f16
        float e[8];
        #pragma unroll
        for (int i = 0; i < 8; ++i) e[i] = exp2f((float)sb[i]);
        union { h16x2 h2[4]; f16x8 v; } pfu;
        #pragma unroll
        for (int i = 0; i < 4; ++i)
          pfu.h2[i] = __builtin_amdgcn_cvt_pkrtz(e[2 * i], e[2 * i + 1]);
        const f16x8 pf = pfu.v;
        o[s][0] = mfma16h(vf[0][fr], pf, o[s][0]);
        o[s][1] = mfma16h(vf[1][fr], pf, o[s][1]);
        lacc[s] = mfma16h(onesv, pf, lacc[s]);  // l += sum_k p (all rows equal)
      }
    }

    #pragma unroll
    for (int s = 0; s < 2; ++s)
      #pragma unroll
      for (int fr = 0; fr < 2; ++fr)
        bc[s][fr] = bn[s][fr];
  }

  // epilogue: l = lacc[s][0] exactly (B-operand reduction spans all lanes)
  #pragma unroll
  for (int s = 0; s < 2; ++s) {
    const float linv = 1.0f / lacc[s][0];
    ushort4 r0, r1;
    unsigned short* r0p = (unsigned short*)&r0;
    unsigned short* r1p = (unsigned short*)&r1;
    #pragma unroll
    for (int i = 0; i < 4; ++i) {
      r0p[i] = f2h(o[s][0][i] * linv);
      r1p[i] = f2h(o[s][1][i] * linv);
    }
    const int row = (b << 10) + q0w + s * 16 + lr;
    *reinterpret_cast<ushort4*>(&AO[row * 256 + h * 32 + lg * 4]) = r0;
    *reinterpret_cast<ushort4*>(&AO[row * 256 + h * 32 + 16 + lg * 4]) = r1;
  }
}

// ---------------- output projection (W-stationary, f16) ------------------------
// grid (64, 4): x = 128-row m-chunk (8 m-tiles), y = col-slab of 64.
__global__ __launch_bounds__(256, 2) void k_oproj(
    const unsigned short* __restrict__ AO, const unsigned short* __restrict__ Wto,
    const float* __restrict__ bo, float* __restrict__ out) {
  const int lane = threadIdx.x & 63;
  const int w = threadIdx.x >> 6;
  const int lr = lane & 15, lg = lane >> 4;
  const int c0 = blockIdx.y * 64 + w * 16;
  const int mbase = blockIdx.x << 7;

  f16x8 bfr[8];
  #pragma unroll
  for (int ks = 0; ks < 8; ++ks)
    bfr[ks] = ldfragh(Wto + (c0 + lr) * 256 + ks * 32 + lg * 8);
  const float bb = bo[c0 + lr];

  for (int mt = 0; mt < 8; ++mt) {
    const int m0 = mbase + mt * 16;
    f16x8 a[8];
    #pragma unroll
    for (int ks = 0; ks < 8; ++ks)
      a[ks] = ldfragh(AO + (m0 + lr) * 256 + ks * 32 + lg * 8);
    f32x4 acc = {0.f, 0.f, 0.f, 0.f};
    #pragma unroll
    for (int ks = 0; ks < 8; ++ks)
      acc = mfma16h(a[ks], bfr[ks], acc);
    #pragma unroll
    for (int i = 0; i < 4; ++i) {
      const int row = m0 + lg * 4 + i;
      out[row * 256 + c0 + lr] = acc[i] + bb;
    }
  }
}

extern "C" void kernel_launch(void* const* d_in, const int* in_sizes, int n_in,
                              void* d_out, int out_size, void* d_ws, size_t ws_size,
                              hipStream_t stream) {
  const float* X   = (const float*)d_in[0];
  const int*   A   = (const int*)d_in[1];
  const float* D   = (const float*)d_in[2];
  const float* Wq  = (const float*)d_in[3];
  const float* bq  = (const float*)d_in[4];
  const float* Wk  = (const float*)d_in[5];
  const float* bk  = (const float*)d_in[6];
  const float* Wv  = (const float*)d_in[7];
  const float* bv  = (const float*)d_in[8];
  const float* Wo  = (const float*)d_in[9];
  const float* bo  = (const float*)d_in[10];
  const float* dsc = (const float*)d_in[11];
  float* out = (float*)d_out;

  unsigned short* ws = (unsigned short*)d_ws;
  unsigned short* Xh   = ws;                   // 2,097,152  (reused as AO later)
  unsigned short* Wt   = ws + 2097152;         //   262,144
  unsigned short* Qb   = ws + 2359296;         // 2,097,152
  unsigned short* Kb   = ws + 4456448;         // 2,097,152
  unsigned short* Vt   = ws + 6553600;         // 2,097,152
  unsigned short* Bias = ws + 8650752;         // 8,388,608  (total ~34.1 MB)
  unsigned short* AO   = Xh;                   // alias: Xh dead after k_qkv

  hipLaunchKernelGGL(k_prep, dim3(11264), dim3(256), 0, stream,
                     X, A, D, dsc, Wq, Wk, Wv, Wo, Xh, Wt, Bias);
  hipLaunchKernelGGL(k_qkv, dim3(32, 12), dim3(256), 0, stream,
                     Xh, Wt, bq, bk, bv, Qb, Kb, Vt);
  hipLaunchKernelGGL(k_attn, dim3(256), dim3(512), 0, stream,
                     Qb, Kb, Vt, Bias, AO);
  hipLaunchKernelGGL(k_oproj, dim3(64, 4), dim3(256), 0, stream,
                     AO, Wt + 196608, bo, out);
}